// Round 2
// 311.412 us; speedup vs baseline: 1.1622x; 1.1622x over previous
//
#include <hip/hip_runtime.h>

#define MAT_N 256
#define TPB   1024
#define ITERS 20

// DPP add: x += row_ror:<N>(x). VALU-pipe cross-lane (NOT the shared DS pipe).
// row_ror is a rotation within each 16-lane row; a 1,2,4,8 rotation chain is an
// all-reduce regardless of rotation direction.
template<int CTRL>
__device__ __forceinline__ float dpp_add(float x) {
    int s = __builtin_amdgcn_update_dpp(0, __builtin_bit_cast(int, x), CTRL, 0xF, 0xF, true);
    return x + __builtin_bit_cast(float, s);
}

// All-reduce over each 32-lane half (lanes grouped by bit 5); every lane gets its
// group's total. 4 DPP row_ror adds (16-lane all-sum, VALU pipe) + one verified
// __shfl_xor(16) for the cross-row combine (DS pipe, 1 op instead of R2's 5).
__device__ __forceinline__ float allreduce32(float x) {
    x = dpp_add<0x121>(x);   // row_ror:1
    x = dpp_add<0x122>(x);   // row_ror:2
    x = dpp_add<0x124>(x);   // row_ror:4
    x = dpp_add<0x128>(x);   // row_ror:8  -> full 16-lane row sum in every lane
    return x + __shfl_xor(x, 16, 64);
}

// Pairwise sum across lane^32 (both halves receive lo+hi). Verified semantics.
__device__ __forceinline__ float pairsum32(float x) {
    return x + __shfl_xor(x, 32, 64);
}

// One block per 256x256 matrix; 1024 threads = 32x32 grid of 8x8 register tiles.
// Multiplicative-domain Sinkhorn: E = exp(x) register-resident (64 f32/thread).
// amdgpu_waves_per_eu(4,4) pins the allocator to a 128-reg budget (4 waves/EU,
// 1 block/CU) so E never spills to scratch.
// R4: rocprof showed the DS pipe (shared, 1/CU) binding at 34% VALUBusy — the
// R2 shuffle butterflies were ~48 ds ops/thread/iter. The 4 in-row butterfly
// levels now run as DPP row_ror adds on the VALU pipe; only the ^16 and ^32
// combines remain on DS (16 ops/thread/iter). R3's permlane16/32_swap variant
// FAILED correctness (absmax 0.218) — those builtins' lane mapping is not what
// was assumed; do not reintroduce without an isolated A/B.
__global__ __launch_bounds__(TPB)
__attribute__((amdgpu_waves_per_eu(4, 4)))
void sinkhorn_kernel(const float* __restrict__ x, float* __restrict__ out)
{
    const int t    = threadIdx.x;
    const int tC   = t & 31;          // 0..31 tile col
    const int row0 = (t >> 5) << 3;
    const int col0 = tC << 3;
    const int w    = t >> 6;          // wave index 0..15
    const int rot  = (tC >> 2) & 7;   // bank-swizzle rotation for partial writes
    const int kb   = (t & 32) >> 3;   // 0 for low half-wave, 4 for high half-wave

    const float* __restrict__ xm = x   + (size_t)blockIdx.x * (MAT_N * MAT_N);
    float* __restrict__       om = out + (size_t)blockIdx.x * (MAT_N * MAT_N);

    __shared__ float part[16][MAT_N];   // pair-reduced column partials, swizzled
    __shared__ float gvec[MAT_N];

    // ---- load tile, E = exp(x) ----
    float E[8][8];
#pragma unroll
    for (int l = 0; l < 8; ++l) {
        const float* rp = xm + (row0 + l) * MAT_N + col0;
        float4 a = *(const float4*)(rp);
        float4 b = *(const float4*)(rp + 4);
        E[l][0] = __expf(a.x); E[l][1] = __expf(a.y);
        E[l][2] = __expf(a.z); E[l][3] = __expf(a.w);
        E[l][4] = __expf(b.x); E[l][5] = __expf(b.y);
        E[l][6] = __expf(b.z); E[l][7] = __expf(b.w);
    }

    float f[8], g[8];
#pragma unroll
    for (int l = 0; l < 8; ++l) f[l] = 1.0f;

    for (int it = 0; it < ITERS; ++it) {
        // ---------- column pass: g = 1 / (E^T f) ----------
        float p[8];
#pragma unroll
        for (int k = 0; k < 8; ++k) p[k] = E[0][k] * f[0];
#pragma unroll
        for (int l = 1; l < 8; ++l)
#pragma unroll
            for (int k = 0; k < 8; ++k) p[k] += E[l][k] * f[l];
        // combine the wave's two tile-rows (lane ^ 32 holds same columns, other row)
#pragma unroll
        for (int k = 0; k < 8; ++k) p[k] = pairsum32(p[k]);
        // full-exec swizzled write: low half-wave writes k=0..3, high writes k=4..7;
        // 64 lanes -> 32 banks x 2 (2-way aliasing is free on CDNA4)
#pragma unroll
        for (int k = 0; k < 4; ++k) {
            const int kk = kb + k;
            part[w][col0 + ((kk + rot) & 7)] = p[kk];
        }
        __syncthreads();
        if (t < MAT_N) {
            const int pos = (t & ~7) | (((t & 7) + (t >> 5)) & 7);  // swizzle inverse
            float s = 0.0f;
#pragma unroll
            for (int r = 0; r < 16; ++r) s += part[r][pos];
            gvec[t] = __builtin_amdgcn_rcpf(s);
        }
        __syncthreads();

        {
            float4 g0 = *(const float4*)&gvec[col0];
            float4 g1 = *(const float4*)&gvec[col0 + 4];
            g[0] = g0.x; g[1] = g0.y; g[2] = g0.z; g[3] = g0.w;
            g[4] = g1.x; g[5] = g1.y; g[6] = g1.z; g[7] = g1.w;
        }

        // ---------- row pass: f = 1 / (E g) ----------
        float q[8];
#pragma unroll
        for (int l = 0; l < 8; ++l) {
            float s = E[l][0] * g[0];
#pragma unroll
            for (int k = 1; k < 8; ++k) s += E[l][k] * g[k];
            q[l] = s;
        }
        // 32-lane all-reduce per tile-row band: DPP ror chain + one shfl_xor(16)
#pragma unroll
        for (int l = 0; l < 8; ++l) {
            q[l] = allreduce32(q[l]);
            f[l] = __builtin_amdgcn_rcpf(q[l]);
        }
    }

    // ---------- output: out = E * f[row] * g[col] ----------
#pragma unroll
    for (int l = 0; l < 8; ++l) {
        float fr = f[l];
        float* rp = om + (row0 + l) * MAT_N + col0;
        *(float4*)(rp)     = make_float4(E[l][0] * fr * g[0], E[l][1] * fr * g[1],
                                         E[l][2] * fr * g[2], E[l][3] * fr * g[3]);
        *(float4*)(rp + 4) = make_float4(E[l][4] * fr * g[4], E[l][5] * fr * g[5],
                                         E[l][6] * fr * g[6], E[l][7] * fr * g[7]);
    }
}

extern "C" void kernel_launch(void* const* d_in, const int* in_sizes, int n_in,
                              void* d_out, int out_size, void* d_ws, size_t ws_size,
                              hipStream_t stream) {
    const float* x = (const float*)d_in[0];
    float* out = (float*)d_out;
    const int nmat = in_sizes[0] / (MAT_N * MAT_N);   // 512
    sinkhorn_kernel<<<nmat, TPB, 0, stream>>>(x, out);
}

// Round 4
// 270.815 us; speedup vs baseline: 1.3364x; 1.1499x over previous
//
#include <hip/hip_runtime.h>

#define MAT_N 256
#define TPB   512
#define ITERS 20

typedef _Float16 half2v __attribute__((ext_vector_type(2)));

// DPP add: x += row_ror:<N>(x). VALU-pipe cross-lane, zero DS traffic.
// row_ror rotates within each 16-lane row; 1,2,4,8 chain = 16-lane all-reduce.
template<int CTRL>
__device__ __forceinline__ float dpp_add(float x) {
    int s = __builtin_amdgcn_update_dpp(0, __builtin_bit_cast(int, x), CTRL, 0xF, 0xF, true);
    return x + __builtin_bit_cast(float, s);
}
__device__ __forceinline__ float allreduce16(float x) {
    x = dpp_add<0x121>(x);   // row_ror:1
    x = dpp_add<0x122>(x);   // row_ror:2
    x = dpp_add<0x124>(x);   // row_ror:4
    x = dpp_add<0x128>(x);   // row_ror:8
    return x;                // full 16-lane row sum in every lane
}

// cvt_pkrtz returns an __fp16-based vector type; bit_cast to our _Float16 half2v.
__device__ __forceinline__ half2v pkrtz(float lo, float hi) {
    return __builtin_bit_cast(half2v, __builtin_amdgcn_cvt_pkrtz(lo, hi));
}

#if __has_builtin(__builtin_amdgcn_fdot2)
__device__ __forceinline__ float dot2(half2v a, half2v b, float c) {
    return __builtin_amdgcn_fdot2(a, b, c, false);   // v_dot2_f32_f16
}
#else
__device__ __forceinline__ float dot2(half2v a, half2v b, float c) {
    return c + (float)a.x * (float)b.x + (float)a.y * (float)b.y;
}
#endif

// R5/R6 restructure: 512-thread blocks (8 waves), thread tile 8 rows x 16 cols,
// E = exp(x) in 64 packed-f16 VGPRs. Total regs ~110 < 128 -> TWO blocks/CU
// (R4 was 1 block/CU: 2 serial grid rounds + unfilled barrier bubbles; counters
// showed VALU 43% / DS ~25% / HBM 16% = latency-bound, nothing saturated).
// - tile-cols = lane bits 0-3, so the row pass reduce is ALL DPP (0 DS ops)
//   and uses v_dot2_f32_f16 (f32 accumulate).
// - col pass: v_pk_fma_f16 over the thread's 8 rows only (f16 error over 8
//   terms ~1e-3 rel), partials written as 2x b128 f16, 32-row f32 reduce by
//   2 waves. No shuffles anywhere (R4 had 16/thread/iter).
// - final output re-reads f32 gvec; E is RNE-converted f16 (2.4e-4 rel).
// R6 fix: cvt_pkrtz return type bit_cast (R5 was a compile error, not a design
// failure).
__global__ __launch_bounds__(TPB)
__attribute__((amdgpu_waves_per_eu(4, 4)))
void sinkhorn_kernel(const float* __restrict__ x, float* __restrict__ out)
{
    const int t    = threadIdx.x;
    const int tC   = t & 15;          // lane bits 0-3: tile col
    const int tR   = t >> 4;          // 0..31: tile row
    const int row0 = tR << 3;
    const int col0 = tC << 4;

    const size_t moff = (size_t)blockIdx.x * (MAT_N * MAT_N);
    const float* __restrict__ xm = x + moff;
    float* __restrict__       om = out + moff;

    __shared__ half2v part[32][132];  // f16 col partials; 132-word row stride
                                      // -> uniform 8 words/bank on b128 writes
    __shared__ float  gvec[MAT_N];

    // ---- load tile, E = exp(x), pack to f16 (RNE) ----
    half2v E[8][8];
#pragma unroll
    for (int l = 0; l < 8; ++l) {
        const float* rp = xm + (row0 + l) * MAT_N + col0;
        float4 a = ((const float4*)rp)[0];
        float4 b = ((const float4*)rp)[1];
        float4 c = ((const float4*)rp)[2];
        float4 d = ((const float4*)rp)[3];
        E[l][0] = (half2v){(_Float16)__expf(a.x), (_Float16)__expf(a.y)};
        E[l][1] = (half2v){(_Float16)__expf(a.z), (_Float16)__expf(a.w)};
        E[l][2] = (half2v){(_Float16)__expf(b.x), (_Float16)__expf(b.y)};
        E[l][3] = (half2v){(_Float16)__expf(b.z), (_Float16)__expf(b.w)};
        E[l][4] = (half2v){(_Float16)__expf(c.x), (_Float16)__expf(c.y)};
        E[l][5] = (half2v){(_Float16)__expf(c.z), (_Float16)__expf(c.w)};
        E[l][6] = (half2v){(_Float16)__expf(d.x), (_Float16)__expf(d.y)};
        E[l][7] = (half2v){(_Float16)__expf(d.z), (_Float16)__expf(d.w)};
    }

    float  f[8];
    half2v f2[8];
#pragma unroll
    for (int l = 0; l < 8; ++l) {
        f[l]  = 1.0f;
        f2[l] = (half2v){(_Float16)1.0f, (_Float16)1.0f};
    }
    half2v g2[8];

    for (int it = 0; it < ITERS; ++it) {
        // ---------- column pass: per-thread 8-row partials (v_pk_fma_f16) ----------
        half2v p2[8];
#pragma unroll
        for (int k = 0; k < 8; ++k) p2[k] = E[0][k] * f2[0];
#pragma unroll
        for (int l = 1; l < 8; ++l)
#pragma unroll
            for (int k = 0; k < 8; ++k) p2[k] += E[l][k] * f2[l];

        // write partials: 2x b128 per thread, padded stride -> near-uniform banks
        {
            half2v* wp = &part[tR][tC << 3];
            float4 w0 = make_float4(__builtin_bit_cast(float, p2[0]),
                                    __builtin_bit_cast(float, p2[1]),
                                    __builtin_bit_cast(float, p2[2]),
                                    __builtin_bit_cast(float, p2[3]));
            float4 w1 = make_float4(__builtin_bit_cast(float, p2[4]),
                                    __builtin_bit_cast(float, p2[5]),
                                    __builtin_bit_cast(float, p2[6]),
                                    __builtin_bit_cast(float, p2[7]));
            ((float4*)wp)[0] = w0;
            ((float4*)wp)[1] = w1;
        }
        __syncthreads();

        // ---------- 32-row reduce by waves 0-1 (other block's waves fill in) ----------
        if (t < 128) {
            float slo = 0.0f, shi = 0.0f;
#pragma unroll
            for (int r = 0; r < 32; ++r) {
                half2v v = part[r][t];      // word t = cols 2t, 2t+1; lanes -> distinct banks
                slo += (float)v.x;
                shi += (float)v.y;
            }
            float2 gw;
            gw.x = __builtin_amdgcn_rcpf(slo);
            gw.y = __builtin_amdgcn_rcpf(shi);
            *(float2*)&gvec[t << 1] = gw;
        }
        __syncthreads();

        // ---------- read g, pack to f16 ----------
        {
            const float* gp = &gvec[col0];
            float4 a = ((const float4*)gp)[0];
            float4 b = ((const float4*)gp)[1];
            float4 c = ((const float4*)gp)[2];
            float4 d = ((const float4*)gp)[3];
            g2[0] = pkrtz(a.x, a.y);
            g2[1] = pkrtz(a.z, a.w);
            g2[2] = pkrtz(b.x, b.y);
            g2[3] = pkrtz(b.z, b.w);
            g2[4] = pkrtz(c.x, c.y);
            g2[5] = pkrtz(c.z, c.w);
            g2[6] = pkrtz(d.x, d.y);
            g2[7] = pkrtz(d.z, d.w);
        }

        // ---------- row pass: dot2 + DPP all-reduce, zero DS ----------
#pragma unroll
        for (int l = 0; l < 8; ++l) {
            float s = dot2(E[l][0], g2[0], 0.0f);
#pragma unroll
            for (int k = 1; k < 8; ++k) s = dot2(E[l][k], g2[k], s);
            s = allreduce16(s);
            f[l] = __builtin_amdgcn_rcpf(s);
            _Float16 h = (_Float16)f[l];
            f2[l] = (half2v){h, h};
        }
    }

    // ---------- output: out = E * f[row] * g[col], g re-read as f32 ----------
    float g[16];
    {
        const float* gp = &gvec[col0];
        float4 a = ((const float4*)gp)[0];
        float4 b = ((const float4*)gp)[1];
        float4 c = ((const float4*)gp)[2];
        float4 d = ((const float4*)gp)[3];
        g[0]=a.x;  g[1]=a.y;  g[2]=a.z;  g[3]=a.w;
        g[4]=b.x;  g[5]=b.y;  g[6]=b.z;  g[7]=b.w;
        g[8]=c.x;  g[9]=c.y;  g[10]=c.z; g[11]=c.w;
        g[12]=d.x; g[13]=d.y; g[14]=d.z; g[15]=d.w;
    }
#pragma unroll
    for (int l = 0; l < 8; ++l) {
        float fr = f[l];
        float* rp = om + (row0 + l) * MAT_N + col0;
        float o[16];
#pragma unroll
        for (int k = 0; k < 8; ++k) {
            o[2*k]   = (float)E[l][k].x * fr * g[2*k];
            o[2*k+1] = (float)E[l][k].y * fr * g[2*k+1];
        }
        ((float4*)rp)[0] = make_float4(o[0],  o[1],  o[2],  o[3]);
        ((float4*)rp)[1] = make_float4(o[4],  o[5],  o[6],  o[7]);
        ((float4*)rp)[2] = make_float4(o[8],  o[9],  o[10], o[11]);
        ((float4*)rp)[3] = make_float4(o[12], o[13], o[14], o[15]);
    }
}

extern "C" void kernel_launch(void* const* d_in, const int* in_sizes, int n_in,
                              void* d_out, int out_size, void* d_ws, size_t ws_size,
                              hipStream_t stream) {
    const float* x = (const float*)d_in[0];
    float* out = (float*)d_out;
    const int nmat = in_sizes[0] / (MAT_N * MAT_N);   // 512
    sinkhorn_kernel<<<nmat, TPB, 0, stream>>>(x, out);
}

// Round 5
// 259.428 us; speedup vs baseline: 1.3951x; 1.0439x over previous
//
#include <hip/hip_runtime.h>

#define MAT_N 256
#define TPB   512
#define ITERS 20
// part row stride in half2-words: >=140 (max swizzled pos 139), == 4 mod 32 so
// consecutive rows step banks by 4, and *4B is 16B-aligned for b128.
#define PSTRIDE 164

typedef _Float16 half2v __attribute__((ext_vector_type(2)));

// DPP add: x += row_ror:<N>(x). VALU-pipe cross-lane, zero DS traffic.
template<int CTRL>
__device__ __forceinline__ float dpp_add(float x) {
    int s = __builtin_amdgcn_update_dpp(0, __builtin_bit_cast(int, x), CTRL, 0xF, 0xF, true);
    return x + __builtin_bit_cast(float, s);
}
// full 16-lane all-reduce (lanes 0-15 of each DPP row)
__device__ __forceinline__ float allreduce16(float x) {
    x = dpp_add<0x121>(x);   // row_ror:1
    x = dpp_add<0x122>(x);   // row_ror:2
    x = dpp_add<0x124>(x);   // row_ror:4
    x = dpp_add<0x128>(x);   // row_ror:8
    return x;
}
// sum over the 4 lanes {c, c+4, c+8, c+12} (same l&3) within each 16-lane row
__device__ __forceinline__ float reduce4spaced(float x) {
    x = dpp_add<0x124>(x);   // row_ror:4
    x = dpp_add<0x128>(x);   // row_ror:8
    return x;
}

// cvt_pkrtz returns an __fp16-based vector; bit_cast to our _Float16 half2v.
__device__ __forceinline__ half2v pkrtz(float lo, float hi) {
    return __builtin_bit_cast(half2v, __builtin_amdgcn_cvt_pkrtz(lo, hi));
}

#if __has_builtin(__builtin_amdgcn_fdot2)
__device__ __forceinline__ float dot2(half2v a, half2v b, float c) {
    return __builtin_amdgcn_fdot2(a, b, c, false);   // v_dot2_f32_f16
}
#else
__device__ __forceinline__ float dot2(half2v a, half2v b, float c) {
    return c + (float)a.x * (float)b.x + (float)a.y * (float)b.y;
}
#endif

// word-position swizzle: logical half2-word w -> p(w) = w + 4*(w>>5).
// Spreads the 8tC-strided access groups across all 32 banks; b128 groups of 4
// words stay contiguous (w>>5 constant within an aligned 8-word group).

// R7: R6 counters showed DS pipe binding again (5.4M conflict cycles = ~1050
// cy/iter/CU; gvec f32 read was 8-way conflicted x4, partial write 4-way) plus
// a 2-wave serial reduce phase. Changes:
//  1. p(w) swizzle on part[] (stride 164 = 4 mod 32) and packed-f16 g2p[]:
//     partial write 2-way (free), g read broadcast/2-way (free), reduce reads
//     conflict-free per 16-lane phase.
//  2. g consumed as packed f16 from g2p (2x b128); f32 gvec only for epilogue.
//  3. all-wave reduce: each thread sums 8 of the 4096 word-reads (word
//     4*(t>>4)+(l&3), rows l>>2 + 4i), DPP row_ror:4/8 combine over the 4
//     spaced lanes. No serial phase, no long add chain, zero shuffles.
__global__ __launch_bounds__(TPB)
__attribute__((amdgpu_waves_per_eu(4, 4)))
void sinkhorn_kernel(const float* __restrict__ x, float* __restrict__ out)
{
    const int t    = threadIdx.x;
    const int tC   = t & 15;          // lane bits 0-3: tile col (16 cols each)
    const int tR   = t >> 4;          // 0..31: tile row (8 rows each)
    const int row0 = tR << 3;
    const int col0 = tC << 4;
    // swizzled base of this thread's 8-word column group: p(8*tC)
    const int pbase = (tC << 3) + ((tC >> 2) << 2);

    // reduce-phase assignment (reuses tR/tC bit fields under different names)
    const int rl   = t & 15;
    const int rw   = ((t >> 4) << 2) + (rl & 3);   // word 0..127 this lane reduces
    const int rrow = rl >> 2;                       // base row 0..3
    const int rpos = rw + ((rw >> 5) << 2);         // p(rw)

    const size_t moff = (size_t)blockIdx.x * (MAT_N * MAT_N);
    const float* __restrict__ xm = x + moff;
    float* __restrict__       om = out + moff;

    __shared__ half2v part[32 * PSTRIDE];  // swizzled col partials (f16 pairs)
    __shared__ half2v g2p[140];            // packed f16 g, swizzled positions
    __shared__ float  gvec[MAT_N];         // f32 g for epilogue only

    // ---- load tile, E = exp(x), pack to f16 (RNE) ----
    half2v E[8][8];
#pragma unroll
    for (int l = 0; l < 8; ++l) {
        const float* rp = xm + (row0 + l) * MAT_N + col0;
        float4 a = ((const float4*)rp)[0];
        float4 b = ((const float4*)rp)[1];
        float4 c = ((const float4*)rp)[2];
        float4 d = ((const float4*)rp)[3];
        E[l][0] = (half2v){(_Float16)__expf(a.x), (_Float16)__expf(a.y)};
        E[l][1] = (half2v){(_Float16)__expf(a.z), (_Float16)__expf(a.w)};
        E[l][2] = (half2v){(_Float16)__expf(b.x), (_Float16)__expf(b.y)};
        E[l][3] = (half2v){(_Float16)__expf(b.z), (_Float16)__expf(b.w)};
        E[l][4] = (half2v){(_Float16)__expf(c.x), (_Float16)__expf(c.y)};
        E[l][5] = (half2v){(_Float16)__expf(c.z), (_Float16)__expf(c.w)};
        E[l][6] = (half2v){(_Float16)__expf(d.x), (_Float16)__expf(d.y)};
        E[l][7] = (half2v){(_Float16)__expf(d.z), (_Float16)__expf(d.w)};
    }

    float  f[8];
    half2v f2[8];
#pragma unroll
    for (int l = 0; l < 8; ++l) {
        f[l]  = 1.0f;
        f2[l] = (half2v){(_Float16)1.0f, (_Float16)1.0f};
    }
    half2v g2[8];

    half2v* const wp = &part[tR * PSTRIDE + pbase];
    const half2v* const rdp = &part[rrow * PSTRIDE + rpos];

    for (int it = 0; it < ITERS; ++it) {
        // ---------- column pass: per-thread 8-row partials (v_pk_fma_f16) ----------
        half2v p2[8];
#pragma unroll
        for (int k = 0; k < 8; ++k) p2[k] = E[0][k] * f2[0];
#pragma unroll
        for (int l = 1; l < 8; ++l)
#pragma unroll
            for (int k = 0; k < 8; ++k) p2[k] += E[l][k] * f2[l];

        // swizzled write: two b128s, 2-way banks (free)
        {
            float4 w0 = make_float4(__builtin_bit_cast(float, p2[0]),
                                    __builtin_bit_cast(float, p2[1]),
                                    __builtin_bit_cast(float, p2[2]),
                                    __builtin_bit_cast(float, p2[3]));
            float4 w1 = make_float4(__builtin_bit_cast(float, p2[4]),
                                    __builtin_bit_cast(float, p2[5]),
                                    __builtin_bit_cast(float, p2[6]),
                                    __builtin_bit_cast(float, p2[7]));
            ((float4*)wp)[0] = w0;
            ((float4*)(wp + 4))[0] = w1;
        }
        __syncthreads();

        // ---------- all-wave column reduce ----------
        // lane sums rows {rrow, rrow+4, ..., rrow+28} of word rw, then DPP
        // row_ror:4/8 combines the 4 spaced lanes holding the same word.
        {
            float slo = 0.0f, shi = 0.0f;
#pragma unroll
            for (int i = 0; i < 8; ++i) {
                half2v v = rdp[(i << 2) * PSTRIDE];
                slo += (float)v.x;
                shi += (float)v.y;
            }
            slo = reduce4spaced(slo);
            shi = reduce4spaced(shi);
            if (rl < 4) {
                float glo = __builtin_amdgcn_rcpf(slo);
                float ghi = __builtin_amdgcn_rcpf(shi);
                *(float2*)&gvec[rw << 1] = make_float2(glo, ghi);
                g2p[rpos] = pkrtz(glo, ghi);
            }
        }
        __syncthreads();

        // ---------- read packed g: two b128s, broadcast/2-way (free) ----------
        {
            const float4 ga = ((const float4*)&g2p[pbase])[0];
            const float4 gb = ((const float4*)&g2p[pbase + 4])[0];
            g2[0] = __builtin_bit_cast(half2v, ga.x);
            g2[1] = __builtin_bit_cast(half2v, ga.y);
            g2[2] = __builtin_bit_cast(half2v, ga.z);
            g2[3] = __builtin_bit_cast(half2v, ga.w);
            g2[4] = __builtin_bit_cast(half2v, gb.x);
            g2[5] = __builtin_bit_cast(half2v, gb.y);
            g2[6] = __builtin_bit_cast(half2v, gb.z);
            g2[7] = __builtin_bit_cast(half2v, gb.w);
        }

        // ---------- row pass: dot2 + DPP all-reduce, zero DS ----------
#pragma unroll
        for (int l = 0; l < 8; ++l) {
            float s = dot2(E[l][0], g2[0], 0.0f);
#pragma unroll
            for (int k = 1; k < 8; ++k) s = dot2(E[l][k], g2[k], s);
            s = allreduce16(s);
            f[l] = __builtin_amdgcn_rcpf(s);
            _Float16 h = (_Float16)f[l];
            f2[l] = (half2v){h, h};
        }
    }

    // ---------- output: out = E * f[row] * g[col], g re-read as f32 ----------
    float g[16];
    {
        const float* gp = &gvec[col0];
        float4 a = ((const float4*)gp)[0];
        float4 b = ((const float4*)gp)[1];
        float4 c = ((const float4*)gp)[2];
        float4 d = ((const float4*)gp)[3];
        g[0]=a.x;  g[1]=a.y;  g[2]=a.z;  g[3]=a.w;
        g[4]=b.x;  g[5]=b.y;  g[6]=b.z;  g[7]=b.w;
        g[8]=c.x;  g[9]=c.y;  g[10]=c.z; g[11]=c.w;
        g[12]=d.x; g[13]=d.y; g[14]=d.z; g[15]=d.w;
    }
#pragma unroll
    for (int l = 0; l < 8; ++l) {
        float fr = f[l];
        float* rp = om + (row0 + l) * MAT_N + col0;
        float o[16];
#pragma unroll
        for (int k = 0; k < 8; ++k) {
            o[2*k]   = (float)E[l][k].x * fr * g[2*k];
            o[2*k+1] = (float)E[l][k].y * fr * g[2*k+1];
        }
        ((float4*)rp)[0] = make_float4(o[0],  o[1],  o[2],  o[3]);
        ((float4*)rp)[1] = make_float4(o[4],  o[5],  o[6],  o[7]);
        ((float4*)rp)[2] = make_float4(o[8],  o[9],  o[10], o[11]);
        ((float4*)rp)[3] = make_float4(o[12], o[13], o[14], o[15]);
    }
}

extern "C" void kernel_launch(void* const* d_in, const int* in_sizes, int n_in,
                              void* d_out, int out_size, void* d_ws, size_t ws_size,
                              hipStream_t stream) {
    const float* x = (const float*)d_in[0];
    float* out = (float*)d_out;
    const int nmat = in_sizes[0] / (MAT_N * MAT_N);   // 512
    sinkhorn_kernel<<<nmat, TPB, 0, stream>>>(x, out);
}